// Round 20
// baseline (216.104 us; speedup 1.0000x reference)
//
#include <hip/hip_runtime.h>
#include <math.h>

// ---------------------------------------------------------------------------
// Net_1503238553644: 2-layer ChebConv(K=2) GNN + linear skips + edge recon loss
// N=13627, E=504378, F=64, H1=300, H2=100, LIN=100
// R20: R18 (best measured) + LDK 72->96: LDS word-stride 48==16 mod 32 ->
//      2-way bank alias (free) instead of 8-way conflict on As/Bs.
// ---------------------------------------------------------------------------

typedef unsigned short ushort_t;
typedef float v2f __attribute__((ext_vector_type(2)));
typedef short bf16x8 __attribute__((ext_vector_type(8)));
typedef float f32x4 __attribute__((ext_vector_type(4)));

#define GBM 64
#define GBN 64
#define GBK 32
#define LDK 96    // bf16 per LDS row: 192B; 48 words == 16 mod 32 -> 2-way (free)
#define HB  256   // histogram blocks (all CUs)
#define PACKN 6816  // ceil(13632/2) packed histogram words

__device__ inline short f2bf(float f) {              // RNE float->bf16
    unsigned u = __float_as_uint(f);
    u += 0x7fff + ((u >> 16) & 1);
    return (short)(u >> 16);
}
__device__ inline float bflo(unsigned w) { return __uint_as_float(w << 16); }
__device__ inline float bfhi(unsigned w) { return __uint_as_float(w & 0xffff0000u); }

// fp8x16 dot (two 128-bit regs = 16 e4m3 each), HW cvt_pk decode
__device__ inline float dot16fp8(uint4 ra, uint4 rb) {
    float dot = 0.0f;
    v2f fa, fb;
    fa = __builtin_amdgcn_cvt_pk_f32_fp8(ra.x, false);
    fb = __builtin_amdgcn_cvt_pk_f32_fp8(rb.x, false);
    dot += fa.x * fb.x + fa.y * fb.y;
    fa = __builtin_amdgcn_cvt_pk_f32_fp8(ra.x, true);
    fb = __builtin_amdgcn_cvt_pk_f32_fp8(rb.x, true);
    dot += fa.x * fb.x + fa.y * fb.y;
    fa = __builtin_amdgcn_cvt_pk_f32_fp8(ra.y, false);
    fb = __builtin_amdgcn_cvt_pk_f32_fp8(rb.y, false);
    dot += fa.x * fb.x + fa.y * fb.y;
    fa = __builtin_amdgcn_cvt_pk_f32_fp8(ra.y, true);
    fb = __builtin_amdgcn_cvt_pk_f32_fp8(rb.y, true);
    dot += fa.x * fb.x + fa.y * fb.y;
    fa = __builtin_amdgcn_cvt_pk_f32_fp8(ra.z, false);
    fb = __builtin_amdgcn_cvt_pk_f32_fp8(rb.z, false);
    dot += fa.x * fb.x + fa.y * fb.y;
    fa = __builtin_amdgcn_cvt_pk_f32_fp8(ra.z, true);
    fb = __builtin_amdgcn_cvt_pk_f32_fp8(rb.z, true);
    dot += fa.x * fb.x + fa.y * fb.y;
    fa = __builtin_amdgcn_cvt_pk_f32_fp8(ra.w, false);
    fb = __builtin_amdgcn_cvt_pk_f32_fp8(rb.w, false);
    dot += fa.x * fb.x + fa.y * fb.y;
    fa = __builtin_amdgcn_cvt_pk_f32_fp8(ra.w, true);
    fb = __builtin_amdgcn_cvt_pk_f32_fp8(rb.w, true);
    dot += fa.x * fb.x + fa.y * fb.y;
    return dot;
}

// fast loss term (same f32 saturation as precise form)
__device__ inline float loss_term(float d, int y) {
    float sg = __builtin_amdgcn_rcpf(1.0f + __expf(-d));
    return y ? __logf(1.0f - sg + 1e-15f) : __logf(sg + 1e-15f);
}

// Pass 1: packed dual LDS histograms (src + dst); tail packs x slice to bf16.
__global__ __launch_bounds__(512) void hist_both_x_kernel(
    const int* __restrict__ ei, const float* __restrict__ x,
    int* __restrict__ degp, int* __restrict__ cntp,
    ushort_t* __restrict__ xb, int Nn, int E) {
    __shared__ int lhs[PACKN];
    __shared__ int lhd[PACKN];
    for (int i = threadIdx.x; i < PACKN; i += 512) { lhs[i] = 0; lhd[i] = 0; }
    __syncthreads();
    const int b = blockIdx.x;
    const int chunk = (E + HB - 1) / HB;
    const int e0 = b * chunk;
    const int e1 = (e0 + chunk < E) ? (e0 + chunk) : E;
    for (int e = e0 + threadIdx.x; e < e1; e += 512) {
        int s = ei[e], d = ei[E + e];
        atomicAdd(&lhs[s >> 1], 1 << ((s & 1) << 4));
        atomicAdd(&lhd[d >> 1], 1 << ((d & 1) << 4));
    }
    __syncthreads();
    int* ds = degp + (size_t)b * PACKN;
    int* cs = cntp + (size_t)b * PACKN;
    for (int i = threadIdx.x; i < PACKN; i += 512) { ds[i] = lhs[i]; cs[i] = lhd[i]; }
    const int rpb = (Nn + HB - 1) / HB;
    const int r0 = b * rpb;
    const int r1 = (r0 + rpb < Nn) ? (r0 + rpb) : Nn;
    for (int i = r0 * 64 + (int)threadIdx.x; i < r1 * 64; i += 512)
        xb[i] = (ushort_t)f2bf(x[i]);
}

// Merge: 4 threads per node. dinv[v]; off[b][v] (ushort); rowptr[v+1].
__global__ void merge_kernel(const int* __restrict__ degp, const int* __restrict__ cntp,
                             ushort_t* __restrict__ off, int Nal,
                             float* __restrict__ dinv, int* __restrict__ rowptr,
                             float* __restrict__ acc, int n) {
    int tid = blockIdx.x * blockDim.x + threadIdx.x;
    if (tid == 0) {
        rowptr[0] = 0;
        acc[0] = 0.0f; acc[1] = 0.0f; acc[2] = 0.0f; acc[3] = 0.0f;
    }
    int v = tid >> 2, qq = tid & 3;
    if (v >= n) return;
    const int vh = v >> 1, sh = (v & 1) << 4;
    const int b0 = qq * (HB / 4), b1 = b0 + HB / 4;
    int dsum = 0, csum = 0;
    for (int b = b0; b < b1; ++b) {
        dsum += (degp[(size_t)b * PACKN + vh] >> sh) & 0xffff;
        csum += (cntp[(size_t)b * PACKN + vh] >> sh) & 0xffff;
    }
    int dtot = dsum;
    dtot += __shfl_xor(dtot, 1, 64);
    dtot += __shfl_xor(dtot, 2, 64);
    int inc = csum;
    int t = __shfl_up(inc, 1, 64); if (qq >= 1) inc += t;
    t = __shfl_up(inc, 2, 64);     if (qq >= 2) inc += t;
    int ex = inc - csum;
    if (qq == 0) dinv[v] = (dtot > 0) ? (1.0f / sqrtf((float)dtot)) : 0.0f;
    if (qq == 3) rowptr[v + 1] = inc;
    int run = ex;
    for (int b = b0; b < b1; ++b) {
        off[(size_t)b * Nal + v] = (ushort_t)run;
        run += (cntp[(size_t)b * PACKN + vh] >> sh) & 0xffff;
    }
}

// single-block inclusive scan of rowptr[1..n]
__global__ void scan_kernel(int* __restrict__ rowptr, int n) {
    __shared__ int wsum[16];
    __shared__ int carry_s;
    if (threadIdx.x == 0) carry_s = 0;
    __syncthreads();
    int nchunk = (n + 1023) / 1024;
    int wid = threadIdx.x >> 6, lane = threadIdx.x & 63;
    for (int c = 0; c < nchunk; ++c) {
        int i = c * 1024 + threadIdx.x;
        int v = (i < n) ? rowptr[i + 1] : 0;
        int s = v;
        for (int off = 1; off < 64; off <<= 1) {
            int t = __shfl_up(s, off, 64);
            if (lane >= off) s += t;
        }
        if (lane == 63) wsum[wid] = s;
        __syncthreads();
        if (wid == 0 && lane < 16) {
            int wsv = wsum[lane];
            for (int off = 1; off < 16; off <<= 1) {
                int t = __shfl_up(wsv, off, 64);
                if (lane >= off) wsv += t;
            }
            wsum[lane] = wsv;
        }
        __syncthreads();
        int base = carry_s + (wid > 0 ? wsum[wid - 1] : 0);
        int inc = base + s;
        if (i < n) rowptr[i + 1] = inc;
        __syncthreads();
        if (threadIdx.x == 1023) carry_s = inc;
        __syncthreads();
    }
}

// Pass 2: fill CSR — rank via packed LDS returning atomic.
__global__ __launch_bounds__(512) void fill_lds_kernel(
    const int* __restrict__ ei, const float* __restrict__ dinv,
    const int* __restrict__ rowptr, const ushort_t* __restrict__ off, int Nal,
    int* __restrict__ colidx, float* __restrict__ wnorm, int E) {
    __shared__ int lh[PACKN];
    for (int i = threadIdx.x; i < PACKN; i += 512) lh[i] = 0;
    __syncthreads();
    const int b = blockIdx.x;
    const int chunk = (E + HB - 1) / HB;
    const int e0 = b * chunk;
    const int e1 = (e0 + chunk < E) ? (e0 + chunk) : E;
    const ushort_t* boff = off + (size_t)b * Nal;
    for (int e = e0 + threadIdx.x; e < e1; e += 512) {
        int s = ei[e], d = ei[E + e];
        int sh = (d & 1) << 4;
        int old = atomicAdd(&lh[d >> 1], 1 << sh);
        int rank = (old >> sh) & 0xffff;
        int slot = rowptr[d] + (int)boff[d] + rank;
        colidx[slot] = s;
        wnorm[slot] = -dinv[s] * dinv[d];
    }
}

// XTb[node] = [ xb[node] | bf16(segsum64(xb))[node] ]
__global__ void xt_kernel(const ushort_t* __restrict__ xb, const int* __restrict__ rowptr,
                          const int* __restrict__ colidx, const float* __restrict__ wnorm,
                          ushort_t* __restrict__ XTb, int n) {
    int node = (blockIdx.x * blockDim.x + threadIdx.x) >> 6;
    if (node >= n) return;
    int lane = threadIdx.x & 63;
    int grp = lane >> 4;
    int l = lane & 15;
    int j0 = rowptr[node], j1 = rowptr[node + 1];
    float a0 = 0, a1 = 0, a2 = 0, a3 = 0;
    int j = j0 + grp;
    if (j < j1) {
        float w = wnorm[j];
        int c = colidx[j];
        uint2 r = ((const uint2*)(xb + (size_t)c * 64))[l];
        for (;;) {
            int jn = j + 4;
            bool more = jn < j1;
            float wn = 0.0f;
            uint2 rn = r;
            if (more) {
                int cn = colidx[jn];
                wn = wnorm[jn];
                rn = ((const uint2*)(xb + (size_t)cn * 64))[l];
            }
            a0 += w * bflo(r.x); a1 += w * bfhi(r.x);
            a2 += w * bflo(r.y); a3 += w * bfhi(r.y);
            if (!more) break;
            j = jn; w = wn; r = rn;
        }
    }
    a0 += __shfl_xor(a0, 16, 64); a0 += __shfl_xor(a0, 32, 64);
    a1 += __shfl_xor(a1, 16, 64); a1 += __shfl_xor(a1, 32, 64);
    a2 += __shfl_xor(a2, 16, 64); a2 += __shfl_xor(a2, 32, 64);
    a3 += __shfl_xor(a3, 16, 64); a3 += __shfl_xor(a3, 32, 64);
    if (grp == 0) {
        uint2 xv = ((const uint2*)(xb + (size_t)node * 64))[l];
        *(uint2*)&XTb[(size_t)node * 128 + l * 4] = xv;
        uint2 p;
        p.x = (unsigned)(unsigned short)f2bf(a0) | ((unsigned)(unsigned short)f2bf(a1) << 16);
        p.y = (unsigned)(unsigned short)f2bf(a2) | ((unsigned)(unsigned short)f2bf(a3) << 16);
        *(uint2*)&XTb[(size_t)node * 128 + 64 + l * 4] = p;
    }
}

// C = A @ Bcat + biascat, bf16 MFMA 64x64x32, 3-region B:
//   col < split:   B0 (ld=split), bias0, Klim=K
//   col < split2:  B1 (ld=split2-split), bias1, Klim=klim1
//   else:          B2 (ld=Ncols-split2), bias2, Klim=klim1
// Output modes: 0: f32 C[row*ldc+col] (relu flag)
//               1: col<split f32 C; col>=split bf16 Cbf[row*128 + col-split]
//               2: all bf16 Cbf[row*ldcbf+col] (relu flag)
//               3: col<split bf16 Cbf[row*ldcbf+col] WITH relu;
//                  col>=split f32 C[row*ldc + col-split] no relu
__global__ __launch_bounds__(256) void gemm_mfma(
    const ushort_t* __restrict__ Abf, int lda,
    const float* __restrict__ B0, const float* __restrict__ B1, const float* __restrict__ B2,
    const float* __restrict__ bias0, const float* __restrict__ bias1, const float* __restrict__ bias2,
    int split, int split2, int klim1,
    float* __restrict__ C, int ldc, ushort_t* __restrict__ Cbf, int ldcbf,
    int cbf_mode, int Nrows, int K, int Ncols, int relu) {
    __shared__ short As[GBM * LDK];
    __shared__ short Bs[GBN * LDK];
    const int bm = blockIdx.y * GBM, bn = blockIdx.x * GBN;
    const int tid = threadIdx.x;
    const int w = tid >> 6, l = tid & 63;
    const int wm = (w >> 1) * 32, wn = (w & 1) * 32;
    const int lr = l & 15;
    const int kg = l >> 4;
    const int arow = tid >> 2, aseg = tid & 3;
    const int bcol = tid & 63, bk2 = (tid >> 6) * 2;

    const int arowg = bm + arow;
    const int bcolg = bn + bcol;
    const float* Bsrc = nullptr;
    int ldb = 1, Klim = K;
    if (bcolg < split)                            { Bsrc = B0 + bcolg; ldb = split; Klim = K; }
    else if (bcolg < split2 && bcolg < Ncols)     { Bsrc = B1 + (bcolg - split); ldb = split2 - split; Klim = klim1; }
    else if (bcolg < Ncols)                       { Bsrc = B2 + (bcolg - split2); ldb = Ncols - split2; Klim = klim1; }

    f32x4 acc00 = {0,0,0,0}, acc01 = {0,0,0,0}, acc10 = {0,0,0,0}, acc11 = {0,0,0,0};

    for (int k0 = 0; k0 < K; k0 += GBK) {
        {
            int kk = k0 + aseg * 8;
            bf16x8 v;
            if (arowg < Nrows && kk + 7 < K) {
                v = *(const bf16x8*)&Abf[(size_t)arowg * lda + kk];
            } else {
#pragma unroll
                for (int i = 0; i < 8; ++i)
                    v[i] = (arowg < Nrows && kk + i < K)
                         ? (short)Abf[(size_t)arowg * lda + kk + i] : (short)0;
            }
            *(bf16x8*)&As[arow * LDK + aseg * 8] = v;
        }
#pragma unroll
        for (int q = 0; q < 4; ++q) {
            int k = q * 8 + bk2;
            unsigned pw = 0u;
            if (Bsrc) {
                float f0 = (k0 + k < Klim) ? Bsrc[(size_t)(k0 + k) * ldb] : 0.0f;
                float f1 = (k0 + k + 1 < Klim) ? Bsrc[(size_t)(k0 + k + 1) * ldb] : 0.0f;
                pw = (unsigned)(unsigned short)f2bf(f0)
                   | ((unsigned)(unsigned short)f2bf(f1) << 16);
            }
            *(unsigned*)&Bs[bcol * LDK + k] = pw;
        }
        __syncthreads();
        bf16x8 a0 = *(const bf16x8*)&As[(wm + lr) * LDK + kg * 8];
        bf16x8 a1 = *(const bf16x8*)&As[(wm + 16 + lr) * LDK + kg * 8];
        bf16x8 b0 = *(const bf16x8*)&Bs[(wn + lr) * LDK + kg * 8];
        bf16x8 b1 = *(const bf16x8*)&Bs[(wn + 16 + lr) * LDK + kg * 8];
        acc00 = __builtin_amdgcn_mfma_f32_16x16x32_bf16(a0, b0, acc00, 0, 0, 0);
        acc01 = __builtin_amdgcn_mfma_f32_16x16x32_bf16(a0, b1, acc01, 0, 0, 0);
        acc10 = __builtin_amdgcn_mfma_f32_16x16x32_bf16(a1, b0, acc10, 0, 0, 0);
        acc11 = __builtin_amdgcn_mfma_f32_16x16x32_bf16(a1, b1, acc11, 0, 0, 0);
        __syncthreads();
    }
#pragma unroll
    for (int i = 0; i < 2; ++i) {
        int rbase = bm + wm + i * 16 + kg * 4;
#pragma unroll
        for (int j = 0; j < 2; ++j) {
            int col = bn + wn + j * 16 + lr;
            if (col >= Ncols) continue;
            float bv;
            if (col < split)       bv = bias0 ? bias0[col] : 0.0f;
            else if (col < split2) bv = bias1 ? bias1[col - split] : 0.0f;
            else                   bv = bias2 ? bias2[col - split2] : 0.0f;
            f32x4 a = (i == 0) ? (j == 0 ? acc00 : acc01) : (j == 0 ? acc10 : acc11);
#pragma unroll
            for (int r = 0; r < 4; ++r) {
                int row = rbase + r;
                if (row >= Nrows) continue;
                float o = a[r] + bv;
                if (cbf_mode == 3) {
                    if (col < split)
                        Cbf[(size_t)row * ldcbf + col] = (ushort_t)f2bf(fmaxf(o, 0.0f));
                    else
                        C[(size_t)row * ldc + (col - split)] = o;
                } else if (cbf_mode == 2) {
                    if (relu) o = fmaxf(o, 0.0f);
                    Cbf[(size_t)row * ldcbf + col] = (ushort_t)f2bf(o);
                } else if (cbf_mode == 1 && col >= split) {
                    Cbf[(size_t)row * 128 + (col - split)] = (ushort_t)f2bf(o);
                } else {
                    if (relu) o = fmaxf(o, 0.0f);
                    C[(size_t)row * ldc + col] = o;
                }
            }
        }
    }
}

// t = segsum(hWb); x1 = relu(G2a + t + b2) — fused epilogue, depth-1 prefetch.
__global__ void segsum_combine1_kernel(const ushort_t* __restrict__ hb,
                                       const int* __restrict__ rowptr, const int* __restrict__ colidx,
                                       const float* __restrict__ wnorm,
                                       const float* __restrict__ G2a, const float* __restrict__ b2,
                                       float* __restrict__ x1, int n) {
    int node = (blockIdx.x * blockDim.x + threadIdx.x) >> 6;
    if (node >= n) return;
    int lane = threadIdx.x & 63;
    int grp = lane >> 4;
    int l = lane & 15;
    int j0 = rowptr[node], j1 = rowptr[node + 1];
    float acc[8] = {};
    int j = j0 + grp;
    if (j < j1) {
        float w = wnorm[j];
        int c = colidx[j];
        uint4 r = ((const uint4*)(hb + (size_t)c * 128))[l];
        for (;;) {
            int jn = j + 4;
            bool more = jn < j1;
            float wn = 0.0f;
            uint4 rn = r;
            if (more) {
                int cn = colidx[jn];
                wn = wnorm[jn];
                rn = ((const uint4*)(hb + (size_t)cn * 128))[l];
            }
            acc[0] += w * bflo(r.x); acc[1] += w * bfhi(r.x);
            acc[2] += w * bflo(r.y); acc[3] += w * bfhi(r.y);
            acc[4] += w * bflo(r.z); acc[5] += w * bfhi(r.z);
            acc[6] += w * bflo(r.w); acc[7] += w * bfhi(r.w);
            if (!more) break;
            j = jn; w = wn; r = rn;
        }
    }
#pragma unroll
    for (int k = 0; k < 8; ++k) {
        acc[k] += __shfl_xor(acc[k], 16, 64);
        acc[k] += __shfl_xor(acc[k], 32, 64);
    }
    if (grp == 0) {
        int f = l * 8;
        if (f < 100) {
            float4 g0 = *(const float4*)&G2a[(size_t)node * 100 + f];
            float4 bv0 = *(const float4*)&b2[f];
            float4 o0;
            o0.x = fmaxf(g0.x + acc[0] + bv0.x, 0.0f);
            o0.y = fmaxf(g0.y + acc[1] + bv0.y, 0.0f);
            o0.z = fmaxf(g0.z + acc[2] + bv0.z, 0.0f);
            o0.w = fmaxf(g0.w + acc[3] + bv0.w, 0.0f);
            *(float4*)&x1[(size_t)node * 100 + f] = o0;
            if (f + 8 <= 100) {
                float4 g1 = *(const float4*)&G2a[(size_t)node * 100 + f + 4];
                float4 bv1 = *(const float4*)&b2[f + 4];
                float4 o1;
                o1.x = fmaxf(g1.x + acc[4] + bv1.x, 0.0f);
                o1.y = fmaxf(g1.y + acc[5] + bv1.y, 0.0f);
                o1.z = fmaxf(g1.z + acc[6] + bv1.z, 0.0f);
                o1.w = fmaxf(g1.w + acc[7] + bv1.w, 0.0f);
                *(float4*)&x1[(size_t)node * 100 + f + 4] = o1;
            }
        }
    }
}

// xo = x1 + relu(S[:,0:100]); zf = fp8(x1 + relu(S[:,100:200]));
// sv[i] = xo[i,:] @ w3b.
__global__ void combine2_kernel(const float* __restrict__ S, const float* __restrict__ x1,
                                const float* __restrict__ w3b,
                                float* __restrict__ xo, unsigned* __restrict__ zf,
                                float* __restrict__ sv, int n) {
    int idx = blockIdx.x * blockDim.x + threadIdx.x;
    if (idx >= n * 32) return;
    int i = idx >> 5, q = idx & 31;
    unsigned w = 0u;
    float part = 0.0f;
    if (q < 25) {
        float4 s1 = *(const float4*)&S[(size_t)i * 200 + q * 4];
        float4 s2 = *(const float4*)&S[(size_t)i * 200 + 100 + q * 4];
        float4 xv = *(const float4*)&x1[(size_t)i * 100 + q * 4];
        float4 a, b;
        a.x = xv.x + fmaxf(s1.x, 0.0f); a.y = xv.y + fmaxf(s1.y, 0.0f);
        a.z = xv.z + fmaxf(s1.z, 0.0f); a.w = xv.w + fmaxf(s1.w, 0.0f);
        b.x = xv.x + fmaxf(s2.x, 0.0f); b.y = xv.y + fmaxf(s2.y, 0.0f);
        b.z = xv.z + fmaxf(s2.z, 0.0f); b.w = xv.w + fmaxf(s2.w, 0.0f);
        *(float4*)&xo[(size_t)i * 100 + q * 4] = a;
        w = (unsigned)__builtin_amdgcn_cvt_pk_fp8_f32(b.x, b.y, 0, false);
        w = (unsigned)__builtin_amdgcn_cvt_pk_fp8_f32(b.z, b.w, (int)w, true);
        float4 wv = *(const float4*)&w3b[q * 4];
        part = a.x * wv.x + a.y * wv.y + a.z * wv.z + a.w * wv.w;
    }
    zf[(size_t)i * 32 + q] = w;
#pragma unroll
    for (int off = 16; off > 0; off >>= 1)
        part += __shfl_xor(part, off, 32);
    if (q == 0) sv[i] = part;
}

// fused pos/neg loss on fp8 z rows: 8 lanes/edge, uint4/lane = full 128B row.
// Two independent pipelined streams per group (VGPR ~28, high occupancy).
__global__ __launch_bounds__(256) void edge_loss_fp8_kernel(
    const unsigned* __restrict__ zf, const int* __restrict__ ei,
    const int* __restrict__ nei, int E, float* __restrict__ accv) {
    const int y = blockIdx.y;
    const int* __restrict__ lst = y ? nei : ei;
    const int l = threadIdx.x & 7;
    const int g = (blockIdx.x * blockDim.x + threadIdx.x) >> 3;
    const int ng = (gridDim.x * blockDim.x) >> 3;
    const int stride2 = 2 * ng;
    float s = 0.0f;
    const int gA = g, gB = g + ng;
    int niterA = (gA < E) ? ((E - 1 - gA) / stride2 + 1) : 0;
    int niterB = (gB < E) ? ((E - 1 - gB) / stride2 + 1) : 0;
    if (niterA > 0) {
        int eB0 = (gB < E) ? gB : (E - 1);
        int eA1 = (gA + stride2 < E) ? (gA + stride2) : (E - 1);
        int eB1 = (gB + stride2 < E) ? (gB + stride2) : (E - 1);
        int aA0 = lst[gA], bA0 = lst[E + gA];
        int aB0 = lst[eB0], bB0 = lst[E + eB0];
        int aA1 = lst[eA1], bA1 = lst[E + eA1];
        int aB1 = lst[eB1], bB1 = lst[E + eB1];
        uint4 raA = *(const uint4*)&zf[(size_t)aA0 * 32 + l * 4];
        uint4 rbA = *(const uint4*)&zf[(size_t)bA0 * 32 + l * 4];
        uint4 raB = *(const uint4*)&zf[(size_t)aB0 * 32 + l * 4];
        uint4 rbB = *(const uint4*)&zf[(size_t)bB0 * 32 + l * 4];
        for (int t = 0; t < niterA; ++t) {
            int eA2 = gA + (t + 2) * stride2; eA2 = (eA2 < E) ? eA2 : (E - 1);
            int eB2 = gB + (t + 2) * stride2; eB2 = (eB2 < E) ? eB2 : (E - 1);
            int aA2 = lst[eA2], bA2 = lst[E + eA2];
            int aB2 = lst[eB2], bB2 = lst[E + eB2];
            uint4 raA1 = *(const uint4*)&zf[(size_t)aA1 * 32 + l * 4];
            uint4 rbA1 = *(const uint4*)&zf[(size_t)bA1 * 32 + l * 4];
            uint4 raB1 = *(const uint4*)&zf[(size_t)aB1 * 32 + l * 4];
            uint4 rbB1 = *(const uint4*)&zf[(size_t)bB1 * 32 + l * 4];
            float dA = dot16fp8(raA, rbA);
            float dB = dot16fp8(raB, rbB);
            dA += __shfl_xor(dA, 1, 8); dB += __shfl_xor(dB, 1, 8);
            dA += __shfl_xor(dA, 2, 8); dB += __shfl_xor(dB, 2, 8);
            dA += __shfl_xor(dA, 4, 8); dB += __shfl_xor(dB, 4, 8);
            if (l == 0) {
                s += loss_term(dA, y);
                if (t < niterB) s += loss_term(dB, y);
            }
            aA1 = aA2; bA1 = bA2; aB1 = aB2; bB1 = bB2;
            raA = raA1; rbA = rbA1; raB = raB1; rbB = rbB1;
        }
    }
    __shared__ float red[256];
    red[threadIdx.x] = s;
    __syncthreads();
    for (int st = 128; st > 0; st >>= 1) {
        if (threadIdx.x < st) red[threadIdx.x] += red[threadIdx.x + st];
        __syncthreads();
    }
    if (threadIdx.x == 0) atomicAdd(&accv[y], red[0]);
}

// out[i] = xo[i,:]@W3[0] + b3 + sum_j wnorm[j]*sv[colidx[j]]; thread 0 tail.
__global__ void out_finalize_kernel(const float* __restrict__ xo, const float* __restrict__ W3,
                                    const float* __restrict__ b3, const int* __restrict__ rowptr,
                                    const int* __restrict__ colidx, const float* __restrict__ wnorm,
                                    const float* __restrict__ sv, const float* __restrict__ accv,
                                    const float* __restrict__ c1, const float* __restrict__ c2,
                                    float* __restrict__ out, int n, int E) {
    int i = blockIdx.x * blockDim.x + threadIdx.x;
    if (i == 0) {
        out[n]     = -(accv[0] + accv[1]) / (float)E;
        out[n + 1] = c1[0];
        out[n + 2] = c2[0];
    }
    if (i >= n) return;
    const float4* a = (const float4*)(xo + (size_t)i * 100);
    const float4* wv = (const float4*)W3;
    float acc = b3[0];
#pragma unroll
    for (int q = 0; q < 25; ++q) {
        float4 va = a[q], vw = wv[q];
        acc += va.x * vw.x + va.y * vw.y + va.z * vw.z + va.w * vw.w;
    }
    int j1 = rowptr[i + 1];
    for (int j = rowptr[i]; j < j1; ++j)
        acc += wnorm[j] * sv[colidx[j]];
    out[i] = acc;
}

extern "C" void kernel_launch(void* const* d_in, const int* in_sizes, int n_in,
                              void* d_out, int out_size, void* d_ws, size_t ws_size,
                              hipStream_t stream) {
    (void)n_in; (void)out_size; (void)ws_size;
    const float* x   = (const float*)d_in[0];
    const int*   ei  = (const int*)d_in[1];
    const int*   nei = (const int*)d_in[2];
    const float* W1  = (const float*)d_in[3];
    const float* b1  = (const float*)d_in[4];
    const float* W2  = (const float*)d_in[5];
    const float* b2  = (const float*)d_in[6];
    const float* W3  = (const float*)d_in[7];
    const float* b3  = (const float*)d_in[8];
    const float* lw1 = (const float*)d_in[9];
    const float* lb1 = (const float*)d_in[10];
    const float* lw2 = (const float*)d_in[11];
    const float* lb2 = (const float*)d_in[12];
    const float* c1  = (const float*)d_in[13];
    const float* c2  = (const float*)d_in[14];

    const int Nn = in_sizes[0] / 64;   // 13627
    const int E  = in_sizes[1] / 2;    // 504378

    const size_t Nal = ((size_t)Nn + 5) & ~(size_t)3;
    const size_t Eal = ((size_t)E + 3) & ~(size_t)3;
    const int LDHB = 304;              // hb bf16 row stride

    float* ws       = (float*)d_ws;
    float* acc      = ws;                           // 4 floats
    float* dinv     = acc + 4;                      // Nal
    int*   rowptr   = (int*)(dinv + Nal);           // Nal
    int*   colidx   = rowptr + Nal;                 // Eal
    float* wnorm    = (float*)(colidx + Eal);       // Eal
    int*   degp     = (int*)(wnorm + Eal);          // HB*PACKN
    int*   cntp     = degp + (size_t)HB * PACKN;    // HB*PACKN
    ushort_t* offus = (ushort_t*)(cntp + (size_t)HB * PACKN);  // HB*Nal
    ushort_t* xb    = offus + (size_t)HB * Nal;     // N*64 bf16
    ushort_t* XTb   = xb + (size_t)Nn * 64;         // N*128 bf16
    ushort_t* hb    = XTb + (size_t)Nn * 128;       // N*304 bf16
    float* G2a      = (float*)(hb + (size_t)Nn * LDHB);  // N*100
    float* x1       = G2a + (size_t)Nn * 100;       // N*100
    float* xo       = x1 + (size_t)Nn * 100;        // N*100
    float* S        = xo + (size_t)Nn * 100;        // N*200
    size_t zoff     = (size_t)(S + (size_t)Nn * 200 - ws);
    zoff = (zoff + 31) & ~(size_t)31;
    unsigned* zf    = (unsigned*)(ws + zoff);       // N*32 words
    size_t hoff2    = zoff + (size_t)Nn * 32 + 63;
    hoff2 &= ~(size_t)63;
    ushort_t* hWb   = (ushort_t*)(ws + hoff2);      // N*128 bf16
    float* sv       = ws + hoff2 + (size_t)Nn * 64; // Nal
    const int MB = (Nn + GBM - 1) / GBM;

    // --- CSR build + x bf16 pack ---
    hist_both_x_kernel<<<HB, 512, 0, stream>>>(ei, x, degp, cntp, xb, Nn, E);
    merge_kernel<<<(4 * Nn + 255) / 256, 256, 0, stream>>>(degp, cntp, offus, (int)Nal,
                                                           dinv, rowptr, acc, Nn);
    scan_kernel<<<1, 1024, 0, stream>>>(rowptr, Nn);
    fill_lds_kernel<<<HB, 512, 0, stream>>>(ei, dinv, rowptr, offus, (int)Nal,
                                            colidx, wnorm, E);

    // --- conv1 + skips fused: XTb = [xb | segsum]; one GEMM over 500 cols:
    //     cols 0-299 -> hb = bf16(relu(XTb@W1 + b1))
    //     cols 300-499 -> S = xb@[lw1|lw2] + [lb1|lb2] (K=64, zero-padded) ---
    xt_kernel<<<(Nn + 3) / 4, 256, 0, stream>>>(xb, rowptr, colidx, wnorm, XTb, Nn);
    gemm_mfma<<<dim3(8, MB), 256, 0, stream>>>(
        XTb, 128, W1, lw1, lw2, b1, lb1, lb2,
        300, 400, 64, S, 200, hb, LDHB, 3, Nn, 128, 500, 1);

    // --- conv2 fused: [G2a | hWb(bf16)] = hb @ [W2[0] | W2[1]] ---
    gemm_mfma<<<dim3(4, MB), 256, 0, stream>>>(
        hb, LDHB, W2, W2 + 300 * 100, W2 + 300 * 100, nullptr, nullptr, nullptr,
        100, 200, 300, G2a, 100, hWb, 0, 1, Nn, 300, 200, 0);
    // x1 = relu(G2a + segsum(hWb) + b2) fused
    segsum_combine1_kernel<<<(Nn + 3) / 4, 256, 0, stream>>>(hWb, rowptr, colidx, wnorm,
                                                             G2a, b2, x1, Nn);

    // --- combine2: xo = x1+relu(S0), zf = fp8(x1+relu(S1)), sv = xo@W3[1] ---
    combine2_kernel<<<(Nn * 32 + 255) / 256, 256, 0, stream>>>(S, x1, W3 + 100,
                                                               xo, zf, sv, Nn);

    // --- edge reconstruction losses, fp8 z, 2 pipelined streams/group ---
    edge_loss_fp8_kernel<<<dim3(1024, 2), 256, 0, stream>>>(zf, ei, nei, E, acc);

    // --- conv3 (width 1) + finalize ---
    out_finalize_kernel<<<(Nn + 255) / 256, 256, 0, stream>>>(
        xo, W3, b3, rowptr, colidx, wnorm, sv, acc, c1, c2, (float*)d_out, Nn, E);
}

// Round 21
// 198.183 us; speedup vs baseline: 1.0904x; 1.0904x over previous
//
#include <hip/hip_runtime.h>
#include <math.h>

// ---------------------------------------------------------------------------
// Net_1503238553644: 2-layer ChebConv(K=2) GNN + linear skips + edge recon loss
// N=13627, E=504378, F=64, H1=300, H2=100, LIN=100
// R21: R18 base (LDK=72) + weights pre-packed to bf16 [col][k] tile-padded
//      tables -> B-staging is 1 vector load + 1 LDS write per thread
//      (was 8 scalar f32 loads + cvts per K-step, re-done per M-tile).
// ---------------------------------------------------------------------------

typedef unsigned short ushort_t;
typedef float v2f __attribute__((ext_vector_type(2)));
typedef short bf16x8 __attribute__((ext_vector_type(8)));
typedef float f32x4 __attribute__((ext_vector_type(4)));

#define GBM 64
#define GBN 64
#define GBK 32
#define LDK 72    // bf16/row: 36 words == 4 mod 32 -> 2-way alias on reads (free)
#define HB  256
#define PACKN 6816
#define LDHB 320  // hb row stride (bf16): 300 valid + 20 exact-zero pad

__device__ inline short f2bf(float f) {              // RNE float->bf16
    unsigned u = __float_as_uint(f);
    u += 0x7fff + ((u >> 16) & 1);
    return (short)(u >> 16);
}
__device__ inline float bflo(unsigned w) { return __uint_as_float(w << 16); }
__device__ inline float bfhi(unsigned w) { return __uint_as_float(w & 0xffff0000u); }

__device__ inline float dot16fp8(uint4 ra, uint4 rb) {
    float dot = 0.0f;
    v2f fa, fb;
    fa = __builtin_amdgcn_cvt_pk_f32_fp8(ra.x, false);
    fb = __builtin_amdgcn_cvt_pk_f32_fp8(rb.x, false);
    dot += fa.x * fb.x + fa.y * fb.y;
    fa = __builtin_amdgcn_cvt_pk_f32_fp8(ra.x, true);
    fb = __builtin_amdgcn_cvt_pk_f32_fp8(rb.x, true);
    dot += fa.x * fb.x + fa.y * fb.y;
    fa = __builtin_amdgcn_cvt_pk_f32_fp8(ra.y, false);
    fb = __builtin_amdgcn_cvt_pk_f32_fp8(rb.y, false);
    dot += fa.x * fb.x + fa.y * fb.y;
    fa = __builtin_amdgcn_cvt_pk_f32_fp8(ra.y, true);
    fb = __builtin_amdgcn_cvt_pk_f32_fp8(rb.y, true);
    dot += fa.x * fb.x + fa.y * fb.y;
    fa = __builtin_amdgcn_cvt_pk_f32_fp8(ra.z, false);
    fb = __builtin_amdgcn_cvt_pk_f32_fp8(rb.z, false);
    dot += fa.x * fb.x + fa.y * fb.y;
    fa = __builtin_amdgcn_cvt_pk_f32_fp8(ra.z, true);
    fb = __builtin_amdgcn_cvt_pk_f32_fp8(rb.z, true);
    dot += fa.x * fb.x + fa.y * fb.y;
    fa = __builtin_amdgcn_cvt_pk_f32_fp8(ra.w, false);
    fb = __builtin_amdgcn_cvt_pk_f32_fp8(rb.w, false);
    dot += fa.x * fb.x + fa.y * fb.y;
    fa = __builtin_amdgcn_cvt_pk_f32_fp8(ra.w, true);
    fb = __builtin_amdgcn_cvt_pk_f32_fp8(rb.w, true);
    dot += fa.x * fb.x + fa.y * fb.y;
    return dot;
}

__device__ inline float loss_term(float d, int y) {
    float sg = __builtin_amdgcn_rcpf(1.0f + __expf(-d));
    return y ? __logf(1.0f - sg + 1e-15f) : __logf(sg + 1e-15f);
}

// Pre-pack weights to bf16 [col][k], tile-padded.
// BtA 576x128: r<300 W1; 300-319 zero; 320-419 lw1 (k<64); 420-519 lw2 (k<64);
// 520-575 zero. ba[576] matching biases. BtB 256x320: r<100 W2[0], 100-199
// W2[1] (k<300); else zero.
__global__ void pack_weights_kernel(const float* __restrict__ W1, const float* __restrict__ b1,
                                    const float* __restrict__ lw1, const float* __restrict__ lb1,
                                    const float* __restrict__ lw2, const float* __restrict__ lb2,
                                    const float* __restrict__ W2,
                                    ushort_t* __restrict__ BtA, float* __restrict__ ba,
                                    ushort_t* __restrict__ BtB) {
    int tid = blockIdx.x * blockDim.x + threadIdx.x;
    int stride = gridDim.x * blockDim.x;
    for (int i = tid; i < 576 * 128; i += stride) {
        int r = i >> 7, k = i & 127;
        float v = 0.0f;
        if (r < 300) v = W1[(size_t)k * 300 + r];
        else if (r >= 320 && r < 420) { if (k < 64) v = lw1[k * 100 + (r - 320)]; }
        else if (r >= 420 && r < 520) { if (k < 64) v = lw2[k * 100 + (r - 420)]; }
        BtA[i] = (ushort_t)f2bf(v);
    }
    for (int i = tid; i < 576; i += stride) {
        float v = 0.0f;
        if (i < 300) v = b1[i];
        else if (i >= 320 && i < 420) v = lb1[i - 320];
        else if (i >= 420 && i < 520) v = lb2[i - 420];
        ba[i] = v;
    }
    for (int i = tid; i < 256 * 320; i += stride) {
        int r = i / 320, k = i - r * 320;
        float v = 0.0f;
        if (k < 300 && r < 200)
            v = (r < 100) ? W2[(size_t)k * 100 + r] : W2[30000 + (size_t)k * 100 + (r - 100)];
        BtB[i] = (ushort_t)f2bf(v);
    }
}

// Pass 1: packed dual LDS histograms (src + dst); tail packs x slice to bf16.
__global__ __launch_bounds__(512) void hist_both_x_kernel(
    const int* __restrict__ ei, const float* __restrict__ x,
    int* __restrict__ degp, int* __restrict__ cntp,
    ushort_t* __restrict__ xb, int Nn, int E) {
    __shared__ int lhs[PACKN];
    __shared__ int lhd[PACKN];
    for (int i = threadIdx.x; i < PACKN; i += 512) { lhs[i] = 0; lhd[i] = 0; }
    __syncthreads();
    const int b = blockIdx.x;
    const int chunk = (E + HB - 1) / HB;
    const int e0 = b * chunk;
    const int e1 = (e0 + chunk < E) ? (e0 + chunk) : E;
    for (int e = e0 + threadIdx.x; e < e1; e += 512) {
        int s = ei[e], d = ei[E + e];
        atomicAdd(&lhs[s >> 1], 1 << ((s & 1) << 4));
        atomicAdd(&lhd[d >> 1], 1 << ((d & 1) << 4));
    }
    __syncthreads();
    int* ds = degp + (size_t)b * PACKN;
    int* cs = cntp + (size_t)b * PACKN;
    for (int i = threadIdx.x; i < PACKN; i += 512) { ds[i] = lhs[i]; cs[i] = lhd[i]; }
    const int rpb = (Nn + HB - 1) / HB;
    const int r0 = b * rpb;
    const int r1 = (r0 + rpb < Nn) ? (r0 + rpb) : Nn;
    for (int i = r0 * 64 + (int)threadIdx.x; i < r1 * 64; i += 512)
        xb[i] = (ushort_t)f2bf(x[i]);
}

// Merge: 4 threads per node. dinv[v]; off[b][v] (ushort); rowptr[v+1].
__global__ void merge_kernel(const int* __restrict__ degp, const int* __restrict__ cntp,
                             ushort_t* __restrict__ off, int Nal,
                             float* __restrict__ dinv, int* __restrict__ rowptr,
                             float* __restrict__ acc, int n) {
    int tid = blockIdx.x * blockDim.x + threadIdx.x;
    if (tid == 0) {
        rowptr[0] = 0;
        acc[0] = 0.0f; acc[1] = 0.0f; acc[2] = 0.0f; acc[3] = 0.0f;
    }
    int v = tid >> 2, qq = tid & 3;
    if (v >= n) return;
    const int vh = v >> 1, sh = (v & 1) << 4;
    const int b0 = qq * (HB / 4), b1 = b0 + HB / 4;
    int dsum = 0, csum = 0;
    for (int b = b0; b < b1; ++b) {
        dsum += (degp[(size_t)b * PACKN + vh] >> sh) & 0xffff;
        csum += (cntp[(size_t)b * PACKN + vh] >> sh) & 0xffff;
    }
    int dtot = dsum;
    dtot += __shfl_xor(dtot, 1, 64);
    dtot += __shfl_xor(dtot, 2, 64);
    int inc = csum;
    int t = __shfl_up(inc, 1, 64); if (qq >= 1) inc += t;
    t = __shfl_up(inc, 2, 64);     if (qq >= 2) inc += t;
    int ex = inc - csum;
    if (qq == 0) dinv[v] = (dtot > 0) ? (1.0f / sqrtf((float)dtot)) : 0.0f;
    if (qq == 3) rowptr[v + 1] = inc;
    int run = ex;
    for (int b = b0; b < b1; ++b) {
        off[(size_t)b * Nal + v] = (ushort_t)run;
        run += (cntp[(size_t)b * PACKN + vh] >> sh) & 0xffff;
    }
}

// single-block inclusive scan of rowptr[1..n]
__global__ void scan_kernel(int* __restrict__ rowptr, int n) {
    __shared__ int wsum[16];
    __shared__ int carry_s;
    if (threadIdx.x == 0) carry_s = 0;
    __syncthreads();
    int nchunk = (n + 1023) / 1024;
    int wid = threadIdx.x >> 6, lane = threadIdx.x & 63;
    for (int c = 0; c < nchunk; ++c) {
        int i = c * 1024 + threadIdx.x;
        int v = (i < n) ? rowptr[i + 1] : 0;
        int s = v;
        for (int off = 1; off < 64; off <<= 1) {
            int t = __shfl_up(s, off, 64);
            if (lane >= off) s += t;
        }
        if (lane == 63) wsum[wid] = s;
        __syncthreads();
        if (wid == 0 && lane < 16) {
            int wsv = wsum[lane];
            for (int off = 1; off < 16; off <<= 1) {
                int t = __shfl_up(wsv, off, 64);
                if (lane >= off) wsv += t;
            }
            wsum[lane] = wsv;
        }
        __syncthreads();
        int base = carry_s + (wid > 0 ? wsum[wid - 1] : 0);
        int inc = base + s;
        if (i < n) rowptr[i + 1] = inc;
        __syncthreads();
        if (threadIdx.x == 1023) carry_s = inc;
        __syncthreads();
    }
}

// Pass 2: fill CSR — rank via packed LDS returning atomic.
__global__ __launch_bounds__(512) void fill_lds_kernel(
    const int* __restrict__ ei, const float* __restrict__ dinv,
    const int* __restrict__ rowptr, const ushort_t* __restrict__ off, int Nal,
    int* __restrict__ colidx, float* __restrict__ wnorm, int E) {
    __shared__ int lh[PACKN];
    for (int i = threadIdx.x; i < PACKN; i += 512) lh[i] = 0;
    __syncthreads();
    const int b = blockIdx.x;
    const int chunk = (E + HB - 1) / HB;
    const int e0 = b * chunk;
    const int e1 = (e0 + chunk < E) ? (e0 + chunk) : E;
    const ushort_t* boff = off + (size_t)b * Nal;
    for (int e = e0 + threadIdx.x; e < e1; e += 512) {
        int s = ei[e], d = ei[E + e];
        int sh = (d & 1) << 4;
        int old = atomicAdd(&lh[d >> 1], 1 << sh);
        int rank = (old >> sh) & 0xffff;
        int slot = rowptr[d] + (int)boff[d] + rank;
        colidx[slot] = s;
        wnorm[slot] = -dinv[s] * dinv[d];
    }
}

// XTb[node] = [ xb[node] | bf16(segsum64(xb))[node] ]
__global__ void xt_kernel(const ushort_t* __restrict__ xb, const int* __restrict__ rowptr,
                          const int* __restrict__ colidx, const float* __restrict__ wnorm,
                          ushort_t* __restrict__ XTb, int n) {
    int node = (blockIdx.x * blockDim.x + threadIdx.x) >> 6;
    if (node >= n) return;
    int lane = threadIdx.x & 63;
    int grp = lane >> 4;
    int l = lane & 15;
    int j0 = rowptr[node], j1 = rowptr[node + 1];
    float a0 = 0, a1 = 0, a2 = 0, a3 = 0;
    int j = j0 + grp;
    if (j < j1) {
        float w = wnorm[j];
        int c = colidx[j];
        uint2 r = ((const uint2*)(xb + (size_t)c * 64))[l];
        for (;;) {
            int jn = j + 4;
            bool more = jn < j1;
            float wn = 0.0f;
            uint2 rn = r;
            if (more) {
                int cn = colidx[jn];
                wn = wnorm[jn];
                rn = ((const uint2*)(xb + (size_t)cn * 64))[l];
            }
            a0 += w * bflo(r.x); a1 += w * bfhi(r.x);
            a2 += w * bflo(r.y); a3 += w * bfhi(r.y);
            if (!more) break;
            j = jn; w = wn; r = rn;
        }
    }
    a0 += __shfl_xor(a0, 16, 64); a0 += __shfl_xor(a0, 32, 64);
    a1 += __shfl_xor(a1, 16, 64); a1 += __shfl_xor(a1, 32, 64);
    a2 += __shfl_xor(a2, 16, 64); a2 += __shfl_xor(a2, 32, 64);
    a3 += __shfl_xor(a3, 16, 64); a3 += __shfl_xor(a3, 32, 64);
    if (grp == 0) {
        uint2 xv = ((const uint2*)(xb + (size_t)node * 64))[l];
        *(uint2*)&XTb[(size_t)node * 128 + l * 4] = xv;
        uint2 p;
        p.x = (unsigned)(unsigned short)f2bf(a0) | ((unsigned)(unsigned short)f2bf(a1) << 16);
        p.y = (unsigned)(unsigned short)f2bf(a2) | ((unsigned)(unsigned short)f2bf(a3) << 16);
        *(uint2*)&XTb[(size_t)node * 128 + 64 + l * 4] = p;
    }
}

// C = A @ Bt^T + bias, bf16 MFMA 64x64x32, LDS-staged, pre-packed bf16 B.
// Bt is [col][k] (ldbt), rows/k tile-padded with zeros. bias f32[col] or null.
// mode 3: col<split -> Cbf[row*ldcbf+col] = bf16(relu(o));
//         col>=split -> C[row*ldc + col-split] = o (no relu)
// mode 1: col<split -> C[row*ldc+col] = o; col>=split -> Cbf[row*128+col-split]
__global__ __launch_bounds__(256) void gemm_mfma(
    const ushort_t* __restrict__ Abf, int lda,
    const ushort_t* __restrict__ Bt, int ldbt,
    const float* __restrict__ bias,
    float* __restrict__ C, int ldc, ushort_t* __restrict__ Cbf, int ldcbf,
    int mode, int split, int Nrows, int K, int Ncols) {
    __shared__ short As[GBM * LDK];
    __shared__ short Bs[GBN * LDK];
    const int bm = blockIdx.y * GBM, bn = blockIdx.x * GBN;
    const int tid = threadIdx.x;
    const int w = tid >> 6, l = tid & 63;
    const int wm = (w >> 1) * 32, wn = (w & 1) * 32;
    const int lr = l & 15, kg = l >> 4;
    const int arow = tid >> 2, aseg = tid & 3;
    const int bcol = tid & 63, bseg = tid >> 6;
    const int arowg = bm + arow;
    const ushort_t* asrc = Abf + (size_t)arowg * lda + aseg * 8;
    const ushort_t* bsrc = Bt + (size_t)(bn + bcol) * ldbt + bseg * 8;
    const bool arow_ok = (arowg < Nrows);

    f32x4 acc00 = {0,0,0,0}, acc01 = {0,0,0,0}, acc10 = {0,0,0,0}, acc11 = {0,0,0,0};

    for (int k0 = 0; k0 < K; k0 += GBK) {
        bf16x8 va = {0,0,0,0,0,0,0,0};
        if (arow_ok) va = *(const bf16x8*)(asrc + k0);
        *(bf16x8*)&As[arow * LDK + aseg * 8] = va;
        *(bf16x8*)&Bs[bcol * LDK + bseg * 8] = *(const bf16x8*)(bsrc + k0);
        __syncthreads();
        bf16x8 a0 = *(const bf16x8*)&As[(wm + lr) * LDK + kg * 8];
        bf16x8 a1 = *(const bf16x8*)&As[(wm + 16 + lr) * LDK + kg * 8];
        bf16x8 b0 = *(const bf16x8*)&Bs[(wn + lr) * LDK + kg * 8];
        bf16x8 b1 = *(const bf16x8*)&Bs[(wn + 16 + lr) * LDK + kg * 8];
        acc00 = __builtin_amdgcn_mfma_f32_16x16x32_bf16(a0, b0, acc00, 0, 0, 0);
        acc01 = __builtin_amdgcn_mfma_f32_16x16x32_bf16(a0, b1, acc01, 0, 0, 0);
        acc10 = __builtin_amdgcn_mfma_f32_16x16x32_bf16(a1, b0, acc10, 0, 0, 0);
        acc11 = __builtin_amdgcn_mfma_f32_16x16x32_bf16(a1, b1, acc11, 0, 0, 0);
        __syncthreads();
    }
#pragma unroll
    for (int i = 0; i < 2; ++i) {
        int rbase = bm + wm + i * 16 + kg * 4;
#pragma unroll
        for (int j = 0; j < 2; ++j) {
            int col = bn + wn + j * 16 + lr;
            if (col >= Ncols) continue;
            float bv = bias ? bias[col] : 0.0f;
            f32x4 a = (i == 0) ? (j == 0 ? acc00 : acc01) : (j == 0 ? acc10 : acc11);
#pragma unroll
            for (int r = 0; r < 4; ++r) {
                int row = rbase + r;
                if (row >= Nrows) continue;
                float o = a[r] + bv;
                if (mode == 3) {
                    if (col < split)
                        Cbf[(size_t)row * ldcbf + col] = (ushort_t)f2bf(fmaxf(o, 0.0f));
                    else
                        C[(size_t)row * ldc + (col - split)] = o;
                } else {
                    if (col < split)
                        C[(size_t)row * ldc + col] = o;
                    else
                        Cbf[(size_t)row * 128 + (col - split)] = (ushort_t)f2bf(o);
                }
            }
        }
    }
}

// t = segsum(hWb); x1 = relu(G2a + t + b2) — fused epilogue, depth-1 prefetch.
__global__ void segsum_combine1_kernel(const ushort_t* __restrict__ hwb,
                                       const int* __restrict__ rowptr, const int* __restrict__ colidx,
                                       const float* __restrict__ wnorm,
                                       const float* __restrict__ G2a, const float* __restrict__ b2,
                                       float* __restrict__ x1, int n) {
    int node = (blockIdx.x * blockDim.x + threadIdx.x) >> 6;
    if (node >= n) return;
    int lane = threadIdx.x & 63;
    int grp = lane >> 4;
    int l = lane & 15;
    int j0 = rowptr[node], j1 = rowptr[node + 1];
    float acc[8] = {};
    int j = j0 + grp;
    if (j < j1) {
        float w = wnorm[j];
        int c = colidx[j];
        uint4 r = ((const uint4*)(hwb + (size_t)c * 128))[l];
        for (;;) {
            int jn = j + 4;
            bool more = jn < j1;
            float wn = 0.0f;
            uint4 rn = r;
            if (more) {
                int cn = colidx[jn];
                wn = wnorm[jn];
                rn = ((const uint4*)(hwb + (size_t)cn * 128))[l];
            }
            acc[0] += w * bflo(r.x); acc[1] += w * bfhi(r.x);
            acc[2] += w * bflo(r.y); acc[3] += w * bfhi(r.y);
            acc[4] += w * bflo(r.z); acc[5] += w * bfhi(r.z);
            acc[6] += w * bflo(r.w); acc[7] += w * bfhi(r.w);
            if (!more) break;
            j = jn; w = wn; r = rn;
        }
    }
#pragma unroll
    for (int k = 0; k < 8; ++k) {
        acc[k] += __shfl_xor(acc[k], 16, 64);
        acc[k] += __shfl_xor(acc[k], 32, 64);
    }
    if (grp == 0) {
        int f = l * 8;
        if (f < 100) {
            float4 g0 = *(const float4*)&G2a[(size_t)node * 100 + f];
            float4 bv0 = *(const float4*)&b2[f];
            float4 o0;
            o0.x = fmaxf(g0.x + acc[0] + bv0.x, 0.0f);
            o0.y = fmaxf(g0.y + acc[1] + bv0.y, 0.0f);
            o0.z = fmaxf(g0.z + acc[2] + bv0.z, 0.0f);
            o0.w = fmaxf(g0.w + acc[3] + bv0.w, 0.0f);
            *(float4*)&x1[(size_t)node * 100 + f] = o0;
            if (f + 8 <= 100) {
                float4 g1 = *(const float4*)&G2a[(size_t)node * 100 + f + 4];
                float4 bv1 = *(const float4*)&b2[f + 4];
                float4 o1;
                o1.x = fmaxf(g1.x + acc[4] + bv1.x, 0.0f);
                o1.y = fmaxf(g1.y + acc[5] + bv1.y, 0.0f);
                o1.z = fmaxf(g1.z + acc[6] + bv1.z, 0.0f);
                o1.w = fmaxf(g1.w + acc[7] + bv1.w, 0.0f);
                *(float4*)&x1[(size_t)node * 100 + f + 4] = o1;
            }
        }
    }
}

// xo = x1 + relu(S[:,0:100]); zf = fp8(x1 + relu(S[:,100:200]));
// sv[i] = xo[i,:] @ w3b.
__global__ void combine2_kernel(const float* __restrict__ S, const float* __restrict__ x1,
                                const float* __restrict__ w3b,
                                float* __restrict__ xo, unsigned* __restrict__ zf,
                                float* __restrict__ sv, int n) {
    int idx = blockIdx.x * blockDim.x + threadIdx.x;
    if (idx >= n * 32) return;
    int i = idx >> 5, q = idx & 31;
    unsigned w = 0u;
    float part = 0.0f;
    if (q < 25) {
        float4 s1 = *(const float4*)&S[(size_t)i * 200 + q * 4];
        float4 s2 = *(const float4*)&S[(size_t)i * 200 + 100 + q * 4];
        float4 xv = *(const float4*)&x1[(size_t)i * 100 + q * 4];
        float4 a, b;
        a.x = xv.x + fmaxf(s1.x, 0.0f); a.y = xv.y + fmaxf(s1.y, 0.0f);
        a.z = xv.z + fmaxf(s1.z, 0.0f); a.w = xv.w + fmaxf(s1.w, 0.0f);
        b.x = xv.x + fmaxf(s2.x, 0.0f); b.y = xv.y + fmaxf(s2.y, 0.0f);
        b.z = xv.z + fmaxf(s2.z, 0.0f); b.w = xv.w + fmaxf(s2.w, 0.0f);
        *(float4*)&xo[(size_t)i * 100 + q * 4] = a;
        w = (unsigned)__builtin_amdgcn_cvt_pk_fp8_f32(b.x, b.y, 0, false);
        w = (unsigned)__builtin_amdgcn_cvt_pk_fp8_f32(b.z, b.w, (int)w, true);
        float4 wv = *(const float4*)&w3b[q * 4];
        part = a.x * wv.x + a.y * wv.y + a.z * wv.z + a.w * wv.w;
    }
    zf[(size_t)i * 32 + q] = w;
#pragma unroll
    for (int off = 16; off > 0; off >>= 1)
        part += __shfl_xor(part, off, 32);
    if (q == 0) sv[i] = part;
}

// fused pos/neg loss on fp8 z rows: 8 lanes/edge, uint4/lane = full 128B row.
__global__ __launch_bounds__(256) void edge_loss_fp8_kernel(
    const unsigned* __restrict__ zf, const int* __restrict__ ei,
    const int* __restrict__ nei, int E, float* __restrict__ accv) {
    const int y = blockIdx.y;
    const int* __restrict__ lst = y ? nei : ei;
    const int l = threadIdx.x & 7;
    const int g = (blockIdx.x * blockDim.x + threadIdx.x) >> 3;
    const int ng = (gridDim.x * blockDim.x) >> 3;
    const int stride2 = 2 * ng;
    float s = 0.0f;
    const int gA = g, gB = g + ng;
    int niterA = (gA < E) ? ((E - 1 - gA) / stride2 + 1) : 0;
    int niterB = (gB < E) ? ((E - 1 - gB) / stride2 + 1) : 0;
    if (niterA > 0) {
        int eB0 = (gB < E) ? gB : (E - 1);
        int eA1 = (gA + stride2 < E) ? (gA + stride2) : (E - 1);
        int eB1 = (gB + stride2 < E) ? (gB + stride2) : (E - 1);
        int aA0 = lst[gA], bA0 = lst[E + gA];
        int aB0 = lst[eB0], bB0 = lst[E + eB0];
        int aA1 = lst[eA1], bA1 = lst[E + eA1];
        int aB1 = lst[eB1], bB1 = lst[E + eB1];
        uint4 raA = *(const uint4*)&zf[(size_t)aA0 * 32 + l * 4];
        uint4 rbA = *(const uint4*)&zf[(size_t)bA0 * 32 + l * 4];
        uint4 raB = *(const uint4*)&zf[(size_t)aB0 * 32 + l * 4];
        uint4 rbB = *(const uint4*)&zf[(size_t)bB0 * 32 + l * 4];
        for (int t = 0; t < niterA; ++t) {
            int eA2 = gA + (t + 2) * stride2; eA2 = (eA2 < E) ? eA2 : (E - 1);
            int eB2 = gB + (t + 2) * stride2; eB2 = (eB2 < E) ? eB2 : (E - 1);
            int aA2 = lst[eA2], bA2 = lst[E + eA2];
            int aB2 = lst[eB2], bB2 = lst[E + eB2];
            uint4 raA1 = *(const uint4*)&zf[(size_t)aA1 * 32 + l * 4];
            uint4 rbA1 = *(const uint4*)&zf[(size_t)bA1 * 32 + l * 4];
            uint4 raB1 = *(const uint4*)&zf[(size_t)aB1 * 32 + l * 4];
            uint4 rbB1 = *(const uint4*)&zf[(size_t)bB1 * 32 + l * 4];
            float dA = dot16fp8(raA, rbA);
            float dB = dot16fp8(raB, rbB);
            dA += __shfl_xor(dA, 1, 8); dB += __shfl_xor(dB, 1, 8);
            dA += __shfl_xor(dA, 2, 8); dB += __shfl_xor(dB, 2, 8);
            dA += __shfl_xor(dA, 4, 8); dB += __shfl_xor(dB, 4, 8);
            if (l == 0) {
                s += loss_term(dA, y);
                if (t < niterB) s += loss_term(dB, y);
            }
            aA1 = aA2; bA1 = bA2; aB1 = aB2; bB1 = bB2;
            raA = raA1; rbA = rbA1; raB = raB1; rbB = rbB1;
        }
    }
    __shared__ float red[256];
    red[threadIdx.x] = s;
    __syncthreads();
    for (int st = 128; st > 0; st >>= 1) {
        if (threadIdx.x < st) red[threadIdx.x] += red[threadIdx.x + st];
        __syncthreads();
    }
    if (threadIdx.x == 0) atomicAdd(&accv[y], red[0]);
}

// out[i] = xo[i,:]@W3[0] + b3 + sum_j wnorm[j]*sv[colidx[j]]; thread 0 tail.
__global__ void out_finalize_kernel(const float* __restrict__ xo, const float* __restrict__ W3,
                                    const float* __restrict__ b3, const int* __restrict__ rowptr,
                                    const int* __restrict__ colidx, const float* __restrict__ wnorm,
                                    const float* __restrict__ sv, const float* __restrict__ accv,
                                    const float* __restrict__ c1, const float* __restrict__ c2,
                                    float* __restrict__ out, int n, int E) {
    int i = blockIdx.x * blockDim.x + threadIdx.x;
    if (i == 0) {
        out[n]     = -(accv[0] + accv[1]) / (float)E;
        out[n + 1] = c1[0];
        out[n + 2] = c2[0];
    }
    if (i >= n) return;
    const float4* a = (const float4*)(xo + (size_t)i * 100);
    const float4* wv = (const float4*)W3;
    float acc = b3[0];
#pragma unroll
    for (int q = 0; q < 25; ++q) {
        float4 va = a[q], vw = wv[q];
        acc += va.x * vw.x + va.y * vw.y + va.z * vw.z + va.w * vw.w;
    }
    int j1 = rowptr[i + 1];
    for (int j = rowptr[i]; j < j1; ++j)
        acc += wnorm[j] * sv[colidx[j]];
    out[i] = acc;
}

extern "C" void kernel_launch(void* const* d_in, const int* in_sizes, int n_in,
                              void* d_out, int out_size, void* d_ws, size_t ws_size,
                              hipStream_t stream) {
    (void)n_in; (void)out_size; (void)ws_size;
    const float* x   = (const float*)d_in[0];
    const int*   ei  = (const int*)d_in[1];
    const int*   nei = (const int*)d_in[2];
    const float* W1  = (const float*)d_in[3];
    const float* b1  = (const float*)d_in[4];
    const float* W2  = (const float*)d_in[5];
    const float* b2  = (const float*)d_in[6];
    const float* W3  = (const float*)d_in[7];
    const float* b3  = (const float*)d_in[8];
    const float* lw1 = (const float*)d_in[9];
    const float* lb1 = (const float*)d_in[10];
    const float* lw2 = (const float*)d_in[11];
    const float* lb2 = (const float*)d_in[12];
    const float* c1  = (const float*)d_in[13];
    const float* c2  = (const float*)d_in[14];

    const int Nn = in_sizes[0] / 64;   // 13627
    const int E  = in_sizes[1] / 2;    // 504378

    const size_t Nal = ((size_t)Nn + 5) & ~(size_t)3;
    const size_t Eal = ((size_t)E + 3) & ~(size_t)3;

    float* ws       = (float*)d_ws;
    float* acc      = ws;                           // 4 floats
    float* dinv     = acc + 4;                      // Nal
    int*   rowptr   = (int*)(dinv + Nal);           // Nal
    int*   colidx   = rowptr + Nal;                 // Eal
    float* wnorm    = (float*)(colidx + Eal);       // Eal
    int*   degp     = (int*)(wnorm + Eal);          // HB*PACKN
    int*   cntp     = degp + (size_t)HB * PACKN;    // HB*PACKN
    ushort_t* offus = (ushort_t*)(cntp + (size_t)HB * PACKN);  // HB*Nal
    ushort_t* xb    = offus + (size_t)HB * Nal;     // Nn*64 bf16
    ushort_t* XTb   = xb + (size_t)Nn * 64;         // Nn*128 bf16
    ushort_t* hb    = XTb + (size_t)Nn * 128;       // Nn*320 bf16
    ushort_t* BtA   = hb + (size_t)Nn * LDHB;       // 576*128 bf16
    ushort_t* BtB   = BtA + 576 * 128;              // 256*320 bf16
    float* ba       = (float*)(BtB + 256 * 320);    // 576 f32
    float* G2a      = ba + 576;                     // Nn*100
    float* x1       = G2a + (size_t)Nn * 100;       // Nn*100
    float* xo       = x1 + (size_t)Nn * 100;        // Nn*100
    float* S        = xo + (size_t)Nn * 100;        // Nn*200
    size_t zoff     = (size_t)(S + (size_t)Nn * 200 - ws);
    zoff = (zoff + 31) & ~(size_t)31;
    unsigned* zf    = (unsigned*)(ws + zoff);       // Nn*32 words
    size_t hoff2    = zoff + (size_t)Nn * 32 + 63;
    hoff2 &= ~(size_t)63;
    ushort_t* hWb   = (ushort_t*)(ws + hoff2);      // Nn*128 bf16
    float* sv       = ws + hoff2 + (size_t)Nn * 64; // Nal
    const int MB = (Nn + GBM - 1) / GBM;

    // --- weight pre-pack ---
    pack_weights_kernel<<<256, 256, 0, stream>>>(W1, b1, lw1, lb1, lw2, lb2, W2,
                                                 BtA, ba, BtB);

    // --- CSR build + x bf16 pack ---
    hist_both_x_kernel<<<HB, 512, 0, stream>>>(ei, x, degp, cntp, xb, Nn, E);
    merge_kernel<<<(4 * Nn + 255) / 256, 256, 0, stream>>>(degp, cntp, offus, (int)Nal,
                                                           dinv, rowptr, acc, Nn);
    scan_kernel<<<1, 1024, 0, stream>>>(rowptr, Nn);
    fill_lds_kernel<<<HB, 512, 0, stream>>>(ei, dinv, rowptr, offus, (int)Nal,
                                            colidx, wnorm, E);

    // --- conv1 + skips fused: XTb = [xb | segsum]; GEMM over 520 cols:
    //     cols 0-319 -> hb (relu; cols 300-319 exact zeros from zero B/bias)
    //     cols 320-519 -> S = xb@[lw1|lw2] + [lb1|lb2] ---
    xt_kernel<<<(Nn + 3) / 4, 256, 0, stream>>>(xb, rowptr, colidx, wnorm, XTb, Nn);
    gemm_mfma<<<dim3(9, MB), 256, 0, stream>>>(
        XTb, 128, BtA, 128, ba, S, 200, hb, LDHB, 3, 320, Nn, 128, 520);

    // --- conv2: [G2a | hWb(bf16)] = hb @ BtB (K padded to 320) ---
    gemm_mfma<<<dim3(4, MB), 256, 0, stream>>>(
        hb, LDHB, BtB, 320, nullptr, G2a, 100, hWb, 0, 1, 100, Nn, 320, 200);
    // x1 = relu(G2a + segsum(hWb) + b2) fused
    segsum_combine1_kernel<<<(Nn + 3) / 4, 256, 0, stream>>>(hWb, rowptr, colidx, wnorm,
                                                             G2a, b2, x1, Nn);

    // --- combine2: xo = x1+relu(S0), zf = fp8(x1+relu(S1)), sv = xo@W3[1] ---
    combine2_kernel<<<(Nn * 32 + 255) / 256, 256, 0, stream>>>(S, x1, W3 + 100,
                                                               xo, zf, sv, Nn);

    // --- edge reconstruction losses, fp8 z, 2 pipelined streams/group ---
    edge_loss_fp8_kernel<<<dim3(1024, 2), 256, 0, stream>>>(zf, ei, nei, E, acc);

    // --- conv3 (width 1) + finalize ---
    out_finalize_kernel<<<(Nn + 255) / 256, 256, 0, stream>>>(
        xo, W3, b3, rowptr, colidx, wnorm, sv, acc, c1, c2, (float*)d_out, Nn, E);
}